// Round 1
// baseline (987.652 us; speedup 1.0000x reference)
//
#include <hip/hip_runtime.h>

typedef short bf16x8 __attribute__((ext_vector_type(8)));
typedef float f32x4 __attribute__((ext_vector_type(4)));

__device__ __forceinline__ unsigned short f2bf(float f) {
  unsigned u = __float_as_uint(f);
  u += 0x7fffu + ((u >> 16) & 1u);
  return (unsigned short)(u >> 16);
}

// ---------------- CSR build ----------------
__global__ void k_hist(const int* __restrict__ dst, int* __restrict__ deg, int E) {
  int e = blockIdx.x * blockDim.x + threadIdx.x;
  if (e < E) atomicAdd(&deg[dst[e]], 1);
}

__global__ void k_scan(const int* __restrict__ deg, int* __restrict__ row_start,
                       int* __restrict__ cursor, int n) {
  __shared__ int part[1024];
  int t = threadIdx.x;
  int chunk = (n + 1023) >> 10;
  int b = t * chunk;
  int e = min(b + chunk, n);
  int s = 0;
  for (int i = b; i < e; i++) s += deg[i];
  part[t] = s;
  __syncthreads();
  for (int off = 1; off < 1024; off <<= 1) {
    int v = (t >= off) ? part[t - off] : 0;
    __syncthreads();
    part[t] += v;
    __syncthreads();
  }
  int run = (t == 0) ? 0 : part[t - 1];
  for (int i = b; i < e; i++) { row_start[i] = run; cursor[i] = run; run += deg[i]; }
  if (t == 1023) row_start[n] = run;
}

__global__ void k_scatter(const int* __restrict__ src, const int* __restrict__ dst,
                          int* __restrict__ cursor, int* __restrict__ edge_src, int E) {
  int e = blockIdx.x * blockDim.x + threadIdx.x;
  if (e < E) {
    int pos = atomicAdd(&cursor[dst[e]], 1);
    edge_src[pos] = src[e];
  }
}

// ---------------- casts / weight repack ----------------
__global__ void k_cast4(const float* __restrict__ x, unsigned short* __restrict__ h, int n4) {
  int i = blockIdx.x * blockDim.x + threadIdx.x;
  if (i < n4) {
    float4 v = ((const float4*)x)[i];
    ushort4 o;
    o.x = f2bf(v.x); o.y = f2bf(v.y); o.z = f2bf(v.z); o.w = f2bf(v.w);
    ((ushort4*)h)[i] = o;
  }
}

// Bt_pq [256 x 128]: rows 0..127 -> P weights (pre_w[:, :128]), rows 128..255 -> Q (pre_w[:, 128:])
__global__ void k_repack_pq(const float* __restrict__ pre_w, unsigned short* __restrict__ Bt) {
  int i = blockIdx.x * blockDim.x + threadIdx.x;
  if (i >= 256 * 128) return;
  int j = i >> 7, k = i & 127;
  float v = (j < 128) ? pre_w[j * 256 + k] : pre_w[(j - 128) * 256 + 128 + k];
  Bt[i] = f2bf(v);
}

// Bt_post [384 x 640]; K: 0..127 = x part (group0 only), 128..639 = agg part; col groups (id, *s, /s)
__global__ void k_repack_post(const float* __restrict__ post_w, unsigned short* __restrict__ Bt) {
  int i = blockIdx.x * blockDim.x + threadIdx.x;
  if (i >= 384 * 640) return;
  int j = i / 640, k = i - j * 640;
  int g = j >> 7, jj = j & 127;
  float v;
  if (k < 128) v = (g == 0) ? post_w[jj * 1664 + k] : 0.0f;
  else v = post_w[jj * 1664 + g * 512 + 128 + (k - 128)];
  Bt[i] = f2bf(v);
}

__global__ void k_repack_lin(const float* __restrict__ lin_w, unsigned short* __restrict__ Bt) {
  int i = blockIdx.x * blockDim.x + threadIdx.x;
  if (i < 128 * 128) Bt[i] = f2bf(lin_w[i]);
}

// ---------------- LDS helpers (XOR swizzle, 128B rows of 64 bf16) ----------------
__device__ __forceinline__ void stageA128(const unsigned short* __restrict__ A, int lda, int M,
                                          int row0, int k0, char* lds) {
  int t = threadIdx.x;
#pragma unroll
  for (int p = 0; p < 4; p++) {
    int r = p * 32 + (t >> 3);
    int ch = t & 7;
    int off = r * 128 + ((ch * 16) ^ ((r & 7) << 4));
    uint4 val = make_uint4(0u, 0u, 0u, 0u);
    int gr = row0 + r;
    if (gr < M) val = *(const uint4*)(A + (size_t)gr * lda + k0 + ch * 8);
    *(uint4*)(lds + off) = val;
  }
}

__device__ __forceinline__ void stageB64(const unsigned short* __restrict__ Bt, int ldb,
                                         int col0, int k0, char* lds) {
  int t = threadIdx.x;
#pragma unroll
  for (int p = 0; p < 2; p++) {
    int r = p * 32 + (t >> 3);
    int ch = t & 7;
    int off = r * 128 + ((ch * 16) ^ ((r & 7) << 4));
    *(uint4*)(lds + off) = *(const uint4*)(Bt + (size_t)(col0 + r) * ldb + k0 + ch * 8);
  }
}

__device__ __forceinline__ bf16x8 readfrag(const char* lds, int row, int ks, int lhi) {
  int inrow = ks * 64 + lhi * 16;
  int off = row * 128 + (inrow ^ ((row & 7) << 4));
  return *(const bf16x8*)(lds + off);
}

// ---------------- GEMM1: C_f32[M x Nout] = A_bf16[M x K] @ Bt^T, ldc given ----------------
__global__ __launch_bounds__(256) void k_gemm_f32(const unsigned short* __restrict__ A,
                                                  const unsigned short* __restrict__ Bt,
                                                  float* __restrict__ C, int M, int K, int ldc) {
  __shared__ __align__(16) char ldsA[128 * 128];
  __shared__ __align__(16) char ldsB[64 * 128];
  int row0 = blockIdx.x * 128;
  int col0 = blockIdx.y * 64;
  int lane = threadIdx.x & 63;
  int w = threadIdx.x >> 6;
  int wr = w >> 1, wc = w & 1;
  int l16 = lane & 15, lhi = lane >> 4;
  f32x4 acc[4][2];
#pragma unroll
  for (int m = 0; m < 4; m++)
#pragma unroll
    for (int n = 0; n < 2; n++) acc[m][n] = (f32x4){0.f, 0.f, 0.f, 0.f};
  int nk = K >> 6;
  for (int kt = 0; kt < nk; kt++) {
    int k0 = kt * 64;
    stageA128(A, K, M, row0, k0, ldsA);
    stageB64(Bt, K, col0, k0, ldsB);
    __syncthreads();
#pragma unroll
    for (int ks = 0; ks < 2; ks++) {
      bf16x8 af[4], bfr[2];
#pragma unroll
      for (int m = 0; m < 4; m++) af[m] = readfrag(ldsA, wr * 64 + m * 16 + l16, ks, lhi);
#pragma unroll
      for (int n = 0; n < 2; n++) bfr[n] = readfrag(ldsB, wc * 32 + n * 16 + l16, ks, lhi);
#pragma unroll
      for (int m = 0; m < 4; m++)
#pragma unroll
        for (int n = 0; n < 2; n++)
          acc[m][n] = __builtin_amdgcn_mfma_f32_16x16x32_bf16(af[m], bfr[n], acc[m][n], 0, 0, 0);
    }
    __syncthreads();
  }
#pragma unroll
  for (int m = 0; m < 4; m++)
#pragma unroll
    for (int n = 0; n < 2; n++)
#pragma unroll
      for (int i = 0; i < 4; i++) {
        int r = row0 + wr * 64 + m * 16 + lhi * 4 + i;
        if (r < M) {
          int c = col0 + wc * 32 + n * 16 + l16;
          C[(size_t)r * ldc + c] = acc[m][n][i];
        }
      }
}

// ---------------- GEMM3: h = bf16(relu(A@lin^T + b)), optional fp32 out ----------------
__global__ __launch_bounds__(256) void k_gemm_out(const unsigned short* __restrict__ A,
                                                   const unsigned short* __restrict__ Bt,
                                                   const float* __restrict__ bias,
                                                   unsigned short* __restrict__ Hout,
                                                   float* __restrict__ Fout,
                                                   int M, int K, int write_f32) {
  __shared__ __align__(16) char ldsA[128 * 128];
  __shared__ __align__(16) char ldsB[64 * 128];
  int row0 = blockIdx.x * 128;
  int col0 = blockIdx.y * 64;
  int lane = threadIdx.x & 63;
  int w = threadIdx.x >> 6;
  int wr = w >> 1, wc = w & 1;
  int l16 = lane & 15, lhi = lane >> 4;
  f32x4 acc[4][2];
#pragma unroll
  for (int m = 0; m < 4; m++)
#pragma unroll
    for (int n = 0; n < 2; n++) acc[m][n] = (f32x4){0.f, 0.f, 0.f, 0.f};
  int nk = K >> 6;
  for (int kt = 0; kt < nk; kt++) {
    int k0 = kt * 64;
    stageA128(A, K, M, row0, k0, ldsA);
    stageB64(Bt, K, col0, k0, ldsB);
    __syncthreads();
#pragma unroll
    for (int ks = 0; ks < 2; ks++) {
      bf16x8 af[4], bfr[2];
#pragma unroll
      for (int m = 0; m < 4; m++) af[m] = readfrag(ldsA, wr * 64 + m * 16 + l16, ks, lhi);
#pragma unroll
      for (int n = 0; n < 2; n++) bfr[n] = readfrag(ldsB, wc * 32 + n * 16 + l16, ks, lhi);
#pragma unroll
      for (int m = 0; m < 4; m++)
#pragma unroll
        for (int n = 0; n < 2; n++)
          acc[m][n] = __builtin_amdgcn_mfma_f32_16x16x32_bf16(af[m], bfr[n], acc[m][n], 0, 0, 0);
    }
    __syncthreads();
  }
#pragma unroll
  for (int m = 0; m < 4; m++)
#pragma unroll
    for (int n = 0; n < 2; n++)
#pragma unroll
      for (int i = 0; i < 4; i++) {
        int r = row0 + wr * 64 + m * 16 + lhi * 4 + i;
        if (r < M) {
          int c = col0 + wc * 32 + n * 16 + l16;
          float v = acc[m][n][i] + bias[c];
          v = fmaxf(v, 0.0f);
          Hout[(size_t)r * 128 + c] = f2bf(v);
          if (write_f32) Fout[(size_t)r * 128 + c] = v;
        }
      }
}

// ---------------- aggregation: per-wave node reduce over CSR ----------------
__global__ __launch_bounds__(256) void k_agg(const float* __restrict__ PQ,
                                              const int* __restrict__ row_start,
                                              const int* __restrict__ edge_src,
                                              const float* __restrict__ pre_b,
                                              const float* __restrict__ adl,
                                              unsigned short* __restrict__ agg,
                                              float* __restrict__ scale,
                                              float* __restrict__ inv_scale, int n) {
  int gtid = blockIdx.x * blockDim.x + threadIdx.x;
  int v = gtid >> 6;
  int lane = threadIdx.x & 63;
  if (v >= n) return;
  int r0 = row_start[v], r1 = row_start[v + 1];
  int dg = r1 - r0;
  float s0 = 0.f, s1 = 0.f, q0 = 0.f, q1 = 0.f;
  float mn0 = INFINITY, mn1 = INFINITY, mx0 = -INFINITY, mx1 = -INFINITY;
  for (int e = r0; e < r1; e++) {
    int s = edge_src[e];
    float2 q = *(const float2*)(PQ + (size_t)s * 256 + 128 + 2 * lane);
    s0 += q.x; s1 += q.y;
    q0 += q.x * q.x; q1 += q.y * q.y;
    mn0 = fminf(mn0, q.x); mn1 = fminf(mn1, q.y);
    mx0 = fmaxf(mx0, q.x); mx1 = fmaxf(mx1, q.y);
  }
  float degf = (float)dg;
  float invd = 1.0f / fmaxf(degf, 1.0f);
  float c0 = PQ[(size_t)v * 256 + 2 * lane] + pre_b[2 * lane];
  float c1 = PQ[(size_t)v * 256 + 2 * lane + 1] + pre_b[2 * lane + 1];
  float meanq0 = s0 * invd, meanq1 = s1 * invd;
  float var0 = fmaxf(q0 * invd - meanq0 * meanq0, 0.f);
  float var1 = fmaxf(q1 * invd - meanq1 * meanq1, 0.f);
  float std0 = sqrtf(var0 + 1e-5f), std1 = sqrtf(var1 + 1e-5f);
  float mean0, mean1, omn0, omn1, omx0, omx1;
  if (dg > 0) {
    mean0 = c0 + meanq0; mean1 = c1 + meanq1;
    omn0 = c0 + mn0; omn1 = c1 + mn1;
    omx0 = c0 + mx0; omx1 = c1 + mx1;
  } else {
    mean0 = mean1 = omn0 = omn1 = omx0 = omx1 = 0.f;
  }
  unsigned short* row = agg + (size_t)v * 512;
  ushort2 w0; w0.x = f2bf(mean0); w0.y = f2bf(mean1);
  ushort2 w1; w1.x = f2bf(omn0);  w1.y = f2bf(omn1);
  ushort2 w2; w2.x = f2bf(omx0);  w2.y = f2bf(omx1);
  ushort2 w3; w3.x = f2bf(std0);  w3.y = f2bf(std1);
  *(ushort2*)(row + 2 * lane) = w0;
  *(ushort2*)(row + 128 + 2 * lane) = w1;
  *(ushort2*)(row + 256 + 2 * lane) = w2;
  *(ushort2*)(row + 384 + 2 * lane) = w3;
  if (lane == 0) {
    float sc = logf(fmaxf(degf, 1.0f) + 1.0f) / adl[0];
    scale[v] = sc;
    inv_scale[v] = 1.0f / sc;
  }
}

// ---------------- GEMM2: y = combine([h|agg] @ Bt_post^T) + post_b ----------------
__global__ __launch_bounds__(512) void k_gemm2(const unsigned short* __restrict__ H,
                                                const unsigned short* __restrict__ AGG,
                                                const unsigned short* __restrict__ Bt,
                                                const float* __restrict__ scale,
                                                const float* __restrict__ inv_scale,
                                                const float* __restrict__ post_b,
                                                unsigned short* __restrict__ Y, int M) {
  __shared__ __align__(16) char ldsA[64 * 128];
  __shared__ __align__(16) char ldsB[384 * 128];
  int row0 = blockIdx.x * 64;
  int lane = threadIdx.x & 63;
  int w = threadIdx.x >> 6;
  int wr = w >> 2, wc = w & 3;
  int l16 = lane & 15, lhi = lane >> 4;
  f32x4 acc[2][6];
#pragma unroll
  for (int m = 0; m < 2; m++)
#pragma unroll
    for (int f = 0; f < 6; f++) acc[m][f] = (f32x4){0.f, 0.f, 0.f, 0.f};
  for (int kt = 0; kt < 10; kt++) {
    int k0 = kt * 64;
    {
      int r = threadIdx.x >> 3;
      int ch = threadIdx.x & 7;
      int kc = k0 + ch * 8;
      int off = r * 128 + ((ch * 16) ^ ((r & 7) << 4));
      uint4 val = make_uint4(0u, 0u, 0u, 0u);
      int gr = row0 + r;
      if (gr < M) {
        if (kc < 128) val = *(const uint4*)(H + (size_t)gr * 128 + kc);
        else val = *(const uint4*)(AGG + (size_t)gr * 512 + (kc - 128));
      }
      *(uint4*)(ldsA + off) = val;
    }
#pragma unroll
    for (int p = 0; p < 6; p++) {
      int idx = p * 512 + threadIdx.x;
      int r = idx >> 3, ch = idx & 7;
      int off = r * 128 + ((ch * 16) ^ ((r & 7) << 4));
      *(uint4*)(ldsB + off) = *(const uint4*)(Bt + (size_t)r * 640 + k0 + ch * 8);
    }
    __syncthreads();
#pragma unroll
    for (int ks = 0; ks < 2; ks++) {
      bf16x8 af[2], bfr[6];
#pragma unroll
      for (int m = 0; m < 2; m++) af[m] = readfrag(ldsA, wr * 32 + m * 16 + l16, ks, lhi);
#pragma unroll
      for (int f = 0; f < 6; f++) {
        int col = (f >> 1) * 128 + wc * 32 + (f & 1) * 16 + l16;
        bfr[f] = readfrag(ldsB, col, ks, lhi);
      }
#pragma unroll
      for (int m = 0; m < 2; m++)
#pragma unroll
        for (int f = 0; f < 6; f++)
          acc[m][f] = __builtin_amdgcn_mfma_f32_16x16x32_bf16(af[m], bfr[f], acc[m][f], 0, 0, 0);
    }
    __syncthreads();
  }
#pragma unroll
  for (int m = 0; m < 2; m++)
#pragma unroll
    for (int i = 0; i < 4; i++) {
      int r = row0 + wr * 32 + m * 16 + lhi * 4 + i;
      if (r >= M) continue;
      float s = scale[r], iv = inv_scale[r];
#pragma unroll
      for (int f01 = 0; f01 < 2; f01++) {
        int c = wc * 32 + f01 * 16 + l16;
        float v = acc[m][f01][i] + s * acc[m][2 + f01][i] + iv * acc[m][4 + f01][i] + post_b[c];
        Y[(size_t)r * 128 + c] = f2bf(v);
      }
    }
}

// ---------------- host ----------------
extern "C" void kernel_launch(void* const* d_in, const int* in_sizes, int n_in,
                              void* d_out, int out_size, void* d_ws, size_t ws_size,
                              hipStream_t stream) {
  const float* x = (const float*)d_in[0];
  const int* eidx = (const int*)d_in[1];
  int n = in_sizes[0] / 128;
  int E = in_sizes[1] / 2;
  const int* src = eidx;
  const int* dst = eidx + E;

  const float *pre_w[5], *pre_b[5], *adl[5], *post_w[5], *post_b[5], *lin_w[5], *lin_b[5];
  for (int i = 0; i < 5; i++) {
    pre_w[i] = (const float*)d_in[2 + i * 7 + 0];
    pre_b[i] = (const float*)d_in[2 + i * 7 + 1];
    adl[i] = (const float*)d_in[2 + i * 7 + 2];
    post_w[i] = (const float*)d_in[2 + i * 7 + 3];
    post_b[i] = (const float*)d_in[2 + i * 7 + 4];
    lin_w[i] = (const float*)d_in[2 + i * 7 + 5];
    lin_b[i] = (const float*)d_in[2 + i * 7 + 6];
  }

  char* ws = (char*)d_ws;
  size_t off = 0;
  auto alloc = [&](size_t bytes) {
    char* p = ws + off;
    off += (bytes + 255) & ~(size_t)255;
    return p;
  };
  unsigned short* h = (unsigned short*)alloc((size_t)n * 128 * 2);
  unsigned short* y = (unsigned short*)alloc((size_t)n * 128 * 2);
  float* PQ = (float*)alloc((size_t)n * 256 * 4);
  unsigned short* agg = (unsigned short*)alloc((size_t)n * 512 * 2);
  float* scale = (float*)alloc((size_t)n * 4);
  float* invs = (float*)alloc((size_t)n * 4);
  int* deg = (int*)alloc((size_t)n * 4);
  int* row_start = (int*)alloc((size_t)(n + 1) * 4);
  int* cursor = (int*)alloc((size_t)n * 4);
  int* edge_src = (int*)alloc((size_t)E * 4);
  unsigned short *Btpq[5], *Btpost[5], *Btlin[5];
  for (int i = 0; i < 5; i++) {
    Btpq[i] = (unsigned short*)alloc(256 * 128 * 2);
    Btpost[i] = (unsigned short*)alloc(384 * 640 * 2);
    Btlin[i] = (unsigned short*)alloc(128 * 128 * 2);
  }

  hipMemsetAsync(deg, 0, (size_t)n * 4, stream);
  k_hist<<<(E + 255) / 256, 256, 0, stream>>>(dst, deg, E);
  k_scan<<<1, 1024, 0, stream>>>(deg, row_start, cursor, n);
  k_scatter<<<(E + 255) / 256, 256, 0, stream>>>(src, dst, cursor, edge_src, E);
  int n4 = n * 128 / 4;
  k_cast4<<<(n4 + 255) / 256, 256, 0, stream>>>(x, h, n4);
  for (int i = 0; i < 5; i++) {
    k_repack_pq<<<(256 * 128 + 255) / 256, 256, 0, stream>>>(pre_w[i], Btpq[i]);
    k_repack_post<<<(384 * 640 + 255) / 256, 256, 0, stream>>>(post_w[i], Btpost[i]);
    k_repack_lin<<<(128 * 128 + 255) / 256, 256, 0, stream>>>(lin_w[i], Btlin[i]);
  }

  for (int L = 0; L < 5; L++) {
    dim3 g1((n + 127) / 128, 4);
    k_gemm_f32<<<g1, 256, 0, stream>>>(h, Btpq[L], PQ, n, 128, 256);
    k_agg<<<(n + 3) / 4, 256, 0, stream>>>(PQ, row_start, edge_src, pre_b[L], adl[L], agg,
                                           scale, invs, n);
    k_gemm2<<<(n + 63) / 64, 512, 0, stream>>>(h, agg, Btpost[L], scale, invs, post_b[L], y, n);
    dim3 g3((n + 127) / 128, 2);
    k_gemm_out<<<g3, 256, 0, stream>>>(y, Btlin[L], lin_b[L], h, (float*)d_out, n, 128,
                                       (L == 4) ? 1 : 0);
  }
}

// Round 2
// 868.480 us; speedup vs baseline: 1.1372x; 1.1372x over previous
//
#include <hip/hip_runtime.h>

typedef short bf16x8 __attribute__((ext_vector_type(8)));
typedef float f32x4 __attribute__((ext_vector_type(4)));

__device__ __forceinline__ unsigned short f2bf(float f) {
  unsigned u = __float_as_uint(f);
  u += 0x7fffu + ((u >> 16) & 1u);
  return (unsigned short)(u >> 16);
}

// ---------------- CSR build ----------------
__global__ void k_hist(const int* __restrict__ dst, int* __restrict__ deg, int E) {
  int e = blockIdx.x * blockDim.x + threadIdx.x;
  if (e < E) atomicAdd(&deg[dst[e]], 1);
}

// hierarchical scan: 1024 elements per block
__global__ __launch_bounds__(256) void k_scan_part(const int* __restrict__ deg,
                                                    int* __restrict__ bsum, int n) {
  int b = blockIdx.x, t = threadIdx.x;
  int base = b * 1024 + t * 4;
  int s = 0;
#pragma unroll
  for (int i = 0; i < 4; i++) {
    int idx = base + i;
    if (idx < n) s += deg[idx];
  }
  for (int off = 1; off < 64; off <<= 1) s += __shfl_xor(s, off);
  __shared__ int ws[4];
  if ((t & 63) == 0) ws[t >> 6] = s;
  __syncthreads();
  if (t == 0) bsum[b] = ws[0] + ws[1] + ws[2] + ws[3];
}

__global__ void k_scan_bsum(const int* __restrict__ bsum, int* __restrict__ boff,
                            int* __restrict__ row_start, int nb, int n) {
  int t = threadIdx.x;  // single wave of 64, nb <= 64
  int orig = (t < nb) ? bsum[t] : 0;
  int v = orig;
  for (int off = 1; off < 64; off <<= 1) {
    int u = __shfl_up(v, off);
    if (t >= off) v += u;
  }
  if (t < nb) boff[t] = v - orig;
  if (t == nb - 1) row_start[n] = v;
}

__global__ __launch_bounds__(256) void k_scan_final(const int* __restrict__ deg,
                                                     const int* __restrict__ boff,
                                                     int* __restrict__ row_start,
                                                     int* __restrict__ cursor, int n) {
  int b = blockIdx.x, t = threadIdx.x;
  int lane = t & 63, wid = t >> 6;
  int base = b * 1024 + t * 4;
  int v[4];
  int s = 0;
#pragma unroll
  for (int i = 0; i < 4; i++) {
    int idx = base + i;
    v[i] = (idx < n) ? deg[idx] : 0;
    s += v[i];
  }
  int sc = s;
  for (int off = 1; off < 64; off <<= 1) {
    int u = __shfl_up(sc, off);
    if (lane >= off) sc += u;
  }
  __shared__ int ws[4];
  if (lane == 63) ws[wid] = sc;
  __syncthreads();
  int wbase = 0;
  for (int i = 0; i < wid; i++) wbase += ws[i];
  int run = boff[b] + wbase + sc - s;
#pragma unroll
  for (int i = 0; i < 4; i++) {
    int idx = base + i;
    if (idx < n) {
      row_start[idx] = run;
      cursor[idx] = run;
      run += v[i];
    }
  }
}

__global__ void k_scatter(const int* __restrict__ src, const int* __restrict__ dst,
                          int* __restrict__ cursor, int* __restrict__ edge_src, int E) {
  int e = blockIdx.x * blockDim.x + threadIdx.x;
  if (e < E) {
    int pos = atomicAdd(&cursor[dst[e]], 1);
    edge_src[pos] = src[e];
  }
}

// ---------------- casts / weight repack ----------------
__global__ void k_cast4(const float* __restrict__ x, unsigned short* __restrict__ h, int n4) {
  int i = blockIdx.x * blockDim.x + threadIdx.x;
  if (i < n4) {
    float4 v = ((const float4*)x)[i];
    ushort4 o;
    o.x = f2bf(v.x); o.y = f2bf(v.y); o.z = f2bf(v.z); o.w = f2bf(v.w);
    ((ushort4*)h)[i] = o;
  }
}

// Bt_pq [256 x 128]: rows 0..127 -> P weights (pre_w[:, :128]), rows 128..255 -> Q (pre_w[:, 128:])
__global__ void k_repack_pq(const float* __restrict__ pre_w, unsigned short* __restrict__ Bt) {
  int i = blockIdx.x * blockDim.x + threadIdx.x;
  if (i >= 256 * 128) return;
  int j = i >> 7, k = i & 127;
  float v = (j < 128) ? pre_w[j * 256 + k] : pre_w[(j - 128) * 256 + 128 + k];
  Bt[i] = f2bf(v);
}

// Bt_post [384 x 640]; K: 0..127 = x part (group0 only), 128..639 = agg part; col groups (id, *s, /s)
__global__ void k_repack_post(const float* __restrict__ post_w, unsigned short* __restrict__ Bt) {
  int i = blockIdx.x * blockDim.x + threadIdx.x;
  if (i >= 384 * 640) return;
  int j = i / 640, k = i - j * 640;
  int g = j >> 7, jj = j & 127;
  float v;
  if (k < 128) v = (g == 0) ? post_w[jj * 1664 + k] : 0.0f;
  else v = post_w[jj * 1664 + g * 512 + 128 + (k - 128)];
  Bt[i] = f2bf(v);
}

__global__ void k_repack_lin(const float* __restrict__ lin_w, unsigned short* __restrict__ Bt) {
  int i = blockIdx.x * blockDim.x + threadIdx.x;
  if (i < 128 * 128) Bt[i] = f2bf(lin_w[i]);
}

// ---------------- LDS helpers (XOR swizzle, 128B rows of 64 bf16) ----------------
__device__ __forceinline__ void stageA128(const unsigned short* __restrict__ A, int lda, int M,
                                          int row0, int k0, char* lds) {
  int t = threadIdx.x;
#pragma unroll
  for (int p = 0; p < 4; p++) {
    int r = p * 32 + (t >> 3);
    int ch = t & 7;
    int off = r * 128 + ((ch * 16) ^ ((r & 7) << 4));
    uint4 val = make_uint4(0u, 0u, 0u, 0u);
    int gr = row0 + r;
    if (gr < M) val = *(const uint4*)(A + (size_t)gr * lda + k0 + ch * 8);
    *(uint4*)(lds + off) = val;
  }
}

__device__ __forceinline__ void stageB64(const unsigned short* __restrict__ Bt, int ldb,
                                         int col0, int k0, char* lds) {
  int t = threadIdx.x;
#pragma unroll
  for (int p = 0; p < 2; p++) {
    int r = p * 32 + (t >> 3);
    int ch = t & 7;
    int off = r * 128 + ((ch * 16) ^ ((r & 7) << 4));
    *(uint4*)(lds + off) = *(const uint4*)(Bt + (size_t)(col0 + r) * ldb + k0 + ch * 8);
  }
}

__device__ __forceinline__ bf16x8 readfrag(const char* lds, int row, int ks, int lhi) {
  int inrow = ks * 64 + lhi * 16;
  int off = row * 128 + (inrow ^ ((row & 7) << 4));
  return *(const bf16x8*)(lds + off);
}

// ---------------- GEMM1: [P_f32 | Q_bf16] = h @ Bt_pq^T ----------------
__global__ __launch_bounds__(256) void k_gemm1(const unsigned short* __restrict__ A,
                                                const unsigned short* __restrict__ Bt,
                                                float* __restrict__ P,
                                                unsigned short* __restrict__ Qb,
                                                int M, int K) {
  __shared__ __align__(16) char ldsA[128 * 128];
  __shared__ __align__(16) char ldsB[64 * 128];
  int row0 = blockIdx.x * 128;
  int col0 = blockIdx.y * 64;
  int lane = threadIdx.x & 63;
  int w = threadIdx.x >> 6;
  int wr = w >> 1, wc = w & 1;
  int l16 = lane & 15, lhi = lane >> 4;
  f32x4 acc[4][2];
#pragma unroll
  for (int m = 0; m < 4; m++)
#pragma unroll
    for (int n = 0; n < 2; n++) acc[m][n] = (f32x4){0.f, 0.f, 0.f, 0.f};
  int nk = K >> 6;
  for (int kt = 0; kt < nk; kt++) {
    int k0 = kt * 64;
    stageA128(A, K, M, row0, k0, ldsA);
    stageB64(Bt, K, col0, k0, ldsB);
    __syncthreads();
#pragma unroll
    for (int ks = 0; ks < 2; ks++) {
      bf16x8 af[4], bfr[2];
#pragma unroll
      for (int m = 0; m < 4; m++) af[m] = readfrag(ldsA, wr * 64 + m * 16 + l16, ks, lhi);
#pragma unroll
      for (int n = 0; n < 2; n++) bfr[n] = readfrag(ldsB, wc * 32 + n * 16 + l16, ks, lhi);
#pragma unroll
      for (int m = 0; m < 4; m++)
#pragma unroll
        for (int n = 0; n < 2; n++)
          acc[m][n] = __builtin_amdgcn_mfma_f32_16x16x32_bf16(af[m], bfr[n], acc[m][n], 0, 0, 0);
    }
    __syncthreads();
  }
#pragma unroll
  for (int m = 0; m < 4; m++)
#pragma unroll
    for (int n = 0; n < 2; n++)
#pragma unroll
      for (int i = 0; i < 4; i++) {
        int r = row0 + wr * 64 + m * 16 + lhi * 4 + i;
        if (r < M) {
          int c = col0 + wc * 32 + n * 16 + l16;
          float v = acc[m][n][i];
          if (c < 128) P[(size_t)r * 128 + c] = v;
          else Qb[(size_t)r * 128 + (c - 128)] = f2bf(v);
        }
      }
}

// ---------------- GEMM3: h = bf16(relu(A@lin^T + b)), optional fp32 out ----------------
__global__ __launch_bounds__(256) void k_gemm_out(const unsigned short* __restrict__ A,
                                                   const unsigned short* __restrict__ Bt,
                                                   const float* __restrict__ bias,
                                                   unsigned short* __restrict__ Hout,
                                                   float* __restrict__ Fout,
                                                   int M, int K, int write_f32) {
  __shared__ __align__(16) char ldsA[128 * 128];
  __shared__ __align__(16) char ldsB[64 * 128];
  int row0 = blockIdx.x * 128;
  int col0 = blockIdx.y * 64;
  int lane = threadIdx.x & 63;
  int w = threadIdx.x >> 6;
  int wr = w >> 1, wc = w & 1;
  int l16 = lane & 15, lhi = lane >> 4;
  f32x4 acc[4][2];
#pragma unroll
  for (int m = 0; m < 4; m++)
#pragma unroll
    for (int n = 0; n < 2; n++) acc[m][n] = (f32x4){0.f, 0.f, 0.f, 0.f};
  int nk = K >> 6;
  for (int kt = 0; kt < nk; kt++) {
    int k0 = kt * 64;
    stageA128(A, K, M, row0, k0, ldsA);
    stageB64(Bt, K, col0, k0, ldsB);
    __syncthreads();
#pragma unroll
    for (int ks = 0; ks < 2; ks++) {
      bf16x8 af[4], bfr[2];
#pragma unroll
      for (int m = 0; m < 4; m++) af[m] = readfrag(ldsA, wr * 64 + m * 16 + l16, ks, lhi);
#pragma unroll
      for (int n = 0; n < 2; n++) bfr[n] = readfrag(ldsB, wc * 32 + n * 16 + l16, ks, lhi);
#pragma unroll
      for (int m = 0; m < 4; m++)
#pragma unroll
        for (int n = 0; n < 2; n++)
          acc[m][n] = __builtin_amdgcn_mfma_f32_16x16x32_bf16(af[m], bfr[n], acc[m][n], 0, 0, 0);
    }
    __syncthreads();
  }
#pragma unroll
  for (int m = 0; m < 4; m++)
#pragma unroll
    for (int n = 0; n < 2; n++)
#pragma unroll
      for (int i = 0; i < 4; i++) {
        int r = row0 + wr * 64 + m * 16 + lhi * 4 + i;
        if (r < M) {
          int c = col0 + wc * 32 + n * 16 + l16;
          float v = acc[m][n][i] + bias[c];
          v = fmaxf(v, 0.0f);
          Hout[(size_t)r * 128 + c] = f2bf(v);
          if (write_f32) Fout[(size_t)r * 128 + c] = v;
        }
      }
}

// ---------------- aggregation: per-wave node reduce over CSR (Q in bf16) ----------------
__global__ __launch_bounds__(256) void k_agg(const float* __restrict__ P,
                                              const unsigned short* __restrict__ Qb,
                                              const int* __restrict__ row_start,
                                              const int* __restrict__ edge_src,
                                              const float* __restrict__ pre_b,
                                              const float* __restrict__ adl,
                                              unsigned short* __restrict__ agg,
                                              float* __restrict__ scale,
                                              float* __restrict__ inv_scale, int n) {
  int gtid = blockIdx.x * blockDim.x + threadIdx.x;
  int v = gtid >> 6;
  int lane = threadIdx.x & 63;
  if (v >= n) return;
  int r0 = row_start[v], r1 = row_start[v + 1];
  int dg = r1 - r0;
  float s0 = 0.f, s1 = 0.f, q0 = 0.f, q1 = 0.f;
  float mn0 = INFINITY, mn1 = INFINITY, mx0 = -INFINITY, mx1 = -INFINITY;
  for (int e = r0; e < r1; e++) {
    int s = edge_src[e];
    unsigned u = *(const unsigned*)(Qb + (size_t)s * 128 + 2 * lane);
    float qx = __uint_as_float(u << 16);
    float qy = __uint_as_float(u & 0xffff0000u);
    s0 += qx; s1 += qy;
    q0 += qx * qx; q1 += qy * qy;
    mn0 = fminf(mn0, qx); mn1 = fminf(mn1, qy);
    mx0 = fmaxf(mx0, qx); mx1 = fmaxf(mx1, qy);
  }
  float degf = (float)dg;
  float invd = 1.0f / fmaxf(degf, 1.0f);
  float c0 = P[(size_t)v * 128 + 2 * lane] + pre_b[2 * lane];
  float c1 = P[(size_t)v * 128 + 2 * lane + 1] + pre_b[2 * lane + 1];
  float meanq0 = s0 * invd, meanq1 = s1 * invd;
  float var0 = fmaxf(q0 * invd - meanq0 * meanq0, 0.f);
  float var1 = fmaxf(q1 * invd - meanq1 * meanq1, 0.f);
  float std0 = sqrtf(var0 + 1e-5f), std1 = sqrtf(var1 + 1e-5f);
  float mean0, mean1, omn0, omn1, omx0, omx1;
  if (dg > 0) {
    mean0 = c0 + meanq0; mean1 = c1 + meanq1;
    omn0 = c0 + mn0; omn1 = c1 + mn1;
    omx0 = c0 + mx0; omx1 = c1 + mx1;
  } else {
    mean0 = mean1 = omn0 = omn1 = omx0 = omx1 = 0.f;
  }
  unsigned short* row = agg + (size_t)v * 512;
  ushort2 w0; w0.x = f2bf(mean0); w0.y = f2bf(mean1);
  ushort2 w1; w1.x = f2bf(omn0);  w1.y = f2bf(omn1);
  ushort2 w2; w2.x = f2bf(omx0);  w2.y = f2bf(omx1);
  ushort2 w3; w3.x = f2bf(std0);  w3.y = f2bf(std1);
  *(ushort2*)(row + 2 * lane) = w0;
  *(ushort2*)(row + 128 + 2 * lane) = w1;
  *(ushort2*)(row + 256 + 2 * lane) = w2;
  *(ushort2*)(row + 384 + 2 * lane) = w3;
  if (lane == 0) {
    float sc = logf(fmaxf(degf, 1.0f) + 1.0f) / adl[0];
    scale[v] = sc;
    inv_scale[v] = 1.0f / sc;
  }
}

// ---------------- GEMM2: y = combine([h|agg] @ Bt_post^T) + post_b ----------------
__global__ __launch_bounds__(512) void k_gemm2(const unsigned short* __restrict__ H,
                                                const unsigned short* __restrict__ AGG,
                                                const unsigned short* __restrict__ Bt,
                                                const float* __restrict__ scale,
                                                const float* __restrict__ inv_scale,
                                                const float* __restrict__ post_b,
                                                unsigned short* __restrict__ Y, int M) {
  __shared__ __align__(16) char ldsA[64 * 128];
  __shared__ __align__(16) char ldsB[384 * 128];
  int row0 = blockIdx.x * 64;
  int lane = threadIdx.x & 63;
  int w = threadIdx.x >> 6;
  int wr = w >> 2, wc = w & 3;
  int l16 = lane & 15, lhi = lane >> 4;
  f32x4 acc[2][6];
#pragma unroll
  for (int m = 0; m < 2; m++)
#pragma unroll
    for (int f = 0; f < 6; f++) acc[m][f] = (f32x4){0.f, 0.f, 0.f, 0.f};
  for (int kt = 0; kt < 10; kt++) {
    int k0 = kt * 64;
    {
      int r = threadIdx.x >> 3;
      int ch = threadIdx.x & 7;
      int kc = k0 + ch * 8;
      int off = r * 128 + ((ch * 16) ^ ((r & 7) << 4));
      uint4 val = make_uint4(0u, 0u, 0u, 0u);
      int gr = row0 + r;
      if (gr < M) {
        if (kc < 128) val = *(const uint4*)(H + (size_t)gr * 128 + kc);
        else val = *(const uint4*)(AGG + (size_t)gr * 512 + (kc - 128));
      }
      *(uint4*)(ldsA + off) = val;
    }
#pragma unroll
    for (int p = 0; p < 6; p++) {
      int idx = p * 512 + threadIdx.x;
      int r = idx >> 3, ch = idx & 7;
      int off = r * 128 + ((ch * 16) ^ ((r & 7) << 4));
      *(uint4*)(ldsB + off) = *(const uint4*)(Bt + (size_t)r * 640 + k0 + ch * 8);
    }
    __syncthreads();
#pragma unroll
    for (int ks = 0; ks < 2; ks++) {
      bf16x8 af[2], bfr[6];
#pragma unroll
      for (int m = 0; m < 2; m++) af[m] = readfrag(ldsA, wr * 32 + m * 16 + l16, ks, lhi);
#pragma unroll
      for (int f = 0; f < 6; f++) {
        int col = (f >> 1) * 128 + wc * 32 + (f & 1) * 16 + l16;
        bfr[f] = readfrag(ldsB, col, ks, lhi);
      }
#pragma unroll
      for (int m = 0; m < 2; m++)
#pragma unroll
        for (int f = 0; f < 6; f++)
          acc[m][f] = __builtin_amdgcn_mfma_f32_16x16x32_bf16(af[m], bfr[f], acc[m][f], 0, 0, 0);
    }
    __syncthreads();
  }
#pragma unroll
  for (int m = 0; m < 2; m++)
#pragma unroll
    for (int i = 0; i < 4; i++) {
      int r = row0 + wr * 32 + m * 16 + lhi * 4 + i;
      if (r >= M) continue;
      float s = scale[r], iv = inv_scale[r];
#pragma unroll
      for (int f01 = 0; f01 < 2; f01++) {
        int c = wc * 32 + f01 * 16 + l16;
        float v = acc[m][f01][i] + s * acc[m][2 + f01][i] + iv * acc[m][4 + f01][i] + post_b[c];
        Y[(size_t)r * 128 + c] = f2bf(v);
      }
    }
}

// ---------------- host ----------------
extern "C" void kernel_launch(void* const* d_in, const int* in_sizes, int n_in,
                              void* d_out, int out_size, void* d_ws, size_t ws_size,
                              hipStream_t stream) {
  const float* x = (const float*)d_in[0];
  const int* eidx = (const int*)d_in[1];
  int n = in_sizes[0] / 128;
  int E = in_sizes[1] / 2;
  const int* src = eidx;
  const int* dst = eidx + E;

  const float *pre_w[5], *pre_b[5], *adl[5], *post_w[5], *post_b[5], *lin_w[5], *lin_b[5];
  for (int i = 0; i < 5; i++) {
    pre_w[i] = (const float*)d_in[2 + i * 7 + 0];
    pre_b[i] = (const float*)d_in[2 + i * 7 + 1];
    adl[i] = (const float*)d_in[2 + i * 7 + 2];
    post_w[i] = (const float*)d_in[2 + i * 7 + 3];
    post_b[i] = (const float*)d_in[2 + i * 7 + 4];
    lin_w[i] = (const float*)d_in[2 + i * 7 + 5];
    lin_b[i] = (const float*)d_in[2 + i * 7 + 6];
  }

  char* ws = (char*)d_ws;
  size_t off = 0;
  auto alloc = [&](size_t bytes) {
    char* p = ws + off;
    off += (bytes + 255) & ~(size_t)255;
    return p;
  };
  unsigned short* h = (unsigned short*)alloc((size_t)n * 128 * 2);
  unsigned short* y = (unsigned short*)alloc((size_t)n * 128 * 2);
  float* P = (float*)alloc((size_t)n * 128 * 4);
  unsigned short* Qb = (unsigned short*)alloc((size_t)n * 128 * 2);
  unsigned short* agg = (unsigned short*)alloc((size_t)n * 512 * 2);
  float* scale = (float*)alloc((size_t)n * 4);
  float* invs = (float*)alloc((size_t)n * 4);
  int* deg = (int*)alloc((size_t)n * 4);
  int* row_start = (int*)alloc((size_t)(n + 1) * 4);
  int* cursor = (int*)alloc((size_t)n * 4);
  int* edge_src = (int*)alloc((size_t)E * 4);
  int nb = (n + 1023) / 1024;
  int* bsum = (int*)alloc((size_t)nb * 4);
  int* boff = (int*)alloc((size_t)nb * 4);
  unsigned short *Btpq[5], *Btpost[5], *Btlin[5];
  for (int i = 0; i < 5; i++) {
    Btpq[i] = (unsigned short*)alloc(256 * 128 * 2);
    Btpost[i] = (unsigned short*)alloc(384 * 640 * 2);
    Btlin[i] = (unsigned short*)alloc(128 * 128 * 2);
  }

  hipMemsetAsync(deg, 0, (size_t)n * 4, stream);
  k_hist<<<(E + 255) / 256, 256, 0, stream>>>(dst, deg, E);
  k_scan_part<<<nb, 256, 0, stream>>>(deg, bsum, n);
  k_scan_bsum<<<1, 64, 0, stream>>>(bsum, boff, row_start, nb, n);
  k_scan_final<<<nb, 256, 0, stream>>>(deg, boff, row_start, cursor, n);
  k_scatter<<<(E + 255) / 256, 256, 0, stream>>>(src, dst, cursor, edge_src, E);
  int n4 = n * 128 / 4;
  k_cast4<<<(n4 + 255) / 256, 256, 0, stream>>>(x, h, n4);
  for (int i = 0; i < 5; i++) {
    k_repack_pq<<<(256 * 128 + 255) / 256, 256, 0, stream>>>(pre_w[i], Btpq[i]);
    k_repack_post<<<(384 * 640 + 255) / 256, 256, 0, stream>>>(post_w[i], Btpost[i]);
    k_repack_lin<<<(128 * 128 + 255) / 256, 256, 0, stream>>>(lin_w[i], Btlin[i]);
  }

  for (int L = 0; L < 5; L++) {
    dim3 g1((n + 127) / 128, 4);
    k_gemm1<<<g1, 256, 0, stream>>>(h, Btpq[L], P, Qb, n, 128);
    k_agg<<<(n + 3) / 4, 256, 0, stream>>>(P, Qb, row_start, edge_src, pre_b[L], adl[L], agg,
                                           scale, invs, n);
    k_gemm2<<<(n + 63) / 64, 512, 0, stream>>>(h, agg, Btpost[L], scale, invs, post_b[L], y, n);
    dim3 g3((n + 127) / 128, 2);
    k_gemm_out<<<g3, 256, 0, stream>>>(y, Btlin[L], lin_b[L], h, (float*)d_out, n, 128,
                                       (L == 4) ? 1 : 0);
  }
}

// Round 3
// 647.072 us; speedup vs baseline: 1.5263x; 1.3422x over previous
//
#include <hip/hip_runtime.h>

typedef short bf16x8 __attribute__((ext_vector_type(8)));
typedef float f32x4 __attribute__((ext_vector_type(4)));

__device__ __forceinline__ unsigned short f2bf(float f) {
  unsigned u = __float_as_uint(f);
  u += 0x7fffu + ((u >> 16) & 1u);
  return (unsigned short)(u >> 16);
}

__device__ __forceinline__ void gload16(const void* g, void* l) {
  __builtin_amdgcn_global_load_lds((const __attribute__((address_space(1))) void*)g,
                                   (__attribute__((address_space(3))) void*)l, 16, 0, 0);
}

// 128B-row swizzled fragment read (64 bf16 per row)
__device__ __forceinline__ bf16x8 rf128(const unsigned char* lds, int row, int pb) {
  return *(const bf16x8*)(lds + row * 128 + (pb ^ ((row & 7) << 4)));
}
// 256B-row swizzled fragment read (128 bf16 per row)
__device__ __forceinline__ bf16x8 rf256(const unsigned char* lds, int row, int pb) {
  return *(const bf16x8*)(lds + row * 256 + (pb ^ ((row & 7) << 4)));
}

// ---------------- CSR build ----------------
__global__ void k_hist(const int* __restrict__ dst, int* __restrict__ deg, int E) {
  int e = blockIdx.x * blockDim.x + threadIdx.x;
  if (e < E) atomicAdd(&deg[dst[e]], 1);
}

__global__ __launch_bounds__(256) void k_scan_part(const int* __restrict__ deg,
                                                    int* __restrict__ bsum, int n) {
  int b = blockIdx.x, t = threadIdx.x;
  int base = b * 1024 + t * 4;
  int s = 0;
#pragma unroll
  for (int i = 0; i < 4; i++) {
    int idx = base + i;
    if (idx < n) s += deg[idx];
  }
  for (int off = 1; off < 64; off <<= 1) s += __shfl_xor(s, off);
  __shared__ int ws[4];
  if ((t & 63) == 0) ws[t >> 6] = s;
  __syncthreads();
  if (t == 0) bsum[b] = ws[0] + ws[1] + ws[2] + ws[3];
}

__global__ void k_scan_bsum(const int* __restrict__ bsum, int* __restrict__ boff,
                            int* __restrict__ row_start, int nb, int n) {
  int t = threadIdx.x;  // single wave, nb <= 64
  int orig = (t < nb) ? bsum[t] : 0;
  int v = orig;
  for (int off = 1; off < 64; off <<= 1) {
    int u = __shfl_up(v, off);
    if (t >= off) v += u;
  }
  if (t < nb) boff[t] = v - orig;
  if (t == nb - 1) row_start[n] = v;
}

__global__ __launch_bounds__(256) void k_scan_final(const int* __restrict__ deg,
                                                     const int* __restrict__ boff,
                                                     int* __restrict__ row_start,
                                                     int* __restrict__ cursor, int n) {
  int b = blockIdx.x, t = threadIdx.x;
  int lane = t & 63, wid = t >> 6;
  int base = b * 1024 + t * 4;
  int v[4];
  int s = 0;
#pragma unroll
  for (int i = 0; i < 4; i++) {
    int idx = base + i;
    v[i] = (idx < n) ? deg[idx] : 0;
    s += v[i];
  }
  int sc = s;
  for (int off = 1; off < 64; off <<= 1) {
    int u = __shfl_up(sc, off);
    if (lane >= off) sc += u;
  }
  __shared__ int ws[4];
  if (lane == 63) ws[wid] = sc;
  __syncthreads();
  int wbase = 0;
  for (int i = 0; i < wid; i++) wbase += ws[i];
  int run = boff[b] + wbase + sc - s;
#pragma unroll
  for (int i = 0; i < 4; i++) {
    int idx = base + i;
    if (idx < n) {
      row_start[idx] = run;
      cursor[idx] = run;
      run += v[i];
    }
  }
}

__global__ void k_scatter(const int* __restrict__ src, const int* __restrict__ dst,
                          int* __restrict__ cursor, int* __restrict__ edge_src, int E) {
  int e = blockIdx.x * blockDim.x + threadIdx.x;
  if (e < E) {
    int pos = atomicAdd(&cursor[dst[e]], 1);
    edge_src[pos] = src[e];
  }
}

// ---------------- cast x -> X.h (row stride 640) ----------------
__global__ void k_cast(const float* __restrict__ x, unsigned short* __restrict__ X, int n) {
  int i = blockIdx.x * blockDim.x + threadIdx.x;  // one per 4 floats
  if (i >= n * 32) return;
  int r = i >> 5, c = (i & 31) * 4;
  float4 v = *(const float4*)(x + (size_t)r * 128 + c);
  ushort4 o;
  o.x = f2bf(v.x); o.y = f2bf(v.y); o.z = f2bf(v.z); o.w = f2bf(v.w);
  *(ushort4*)(X + (size_t)r * 640 + c) = o;
}

// ---------------- weight repacks into pre-swizzled LDS images ----------------
// Wpq image: 256 rows (out col: 0..127 P, 128..255 Q) x 256B (K=128, swizzled)
__global__ void k_repack_pq(const float* __restrict__ pre_w, unsigned char* __restrict__ img) {
  int i = blockIdx.x * blockDim.x + threadIdx.x;
  if (i >= 256 * 128) return;
  int j = i >> 7, k = i & 127;
  float v = (j < 128) ? pre_w[j * 256 + k] : pre_w[(j - 128) * 256 + 128 + k];
  int ch = k >> 3, e = k & 7;
  int off = j * 256 + ((ch * 16) ^ ((j & 7) << 4)) + e * 2;
  *(unsigned short*)(img + off) = f2bf(v);
}

// Bpost image: 10 K-tiles x (384 rows x 128B swizzled) = 480KB
__global__ void k_repack_post(const float* __restrict__ post_w, unsigned char* __restrict__ img) {
  int i = blockIdx.x * blockDim.x + threadIdx.x;
  if (i >= 384 * 640) return;
  int r = i / 640, k = i - r * 640;
  int g = r >> 7, jj = r & 127;
  float v;
  if (k < 128) v = (g == 0) ? post_w[jj * 1664 + k] : 0.0f;
  else v = post_w[jj * 1664 + g * 512 + 128 + (k - 128)];
  int kt = k >> 6, kl = k & 63;
  int ch = kl >> 3, e = kl & 7;
  int off = kt * 49152 + r * 128 + ((ch * 16) ^ ((r & 7) << 4)) + e * 2;
  *(unsigned short*)(img + off) = f2bf(v);
}

// lin image: 128 rows x 256B (K=128, swizzled) = 32KB
__global__ void k_repack_lin(const float* __restrict__ lin_w, unsigned char* __restrict__ img) {
  int i = blockIdx.x * blockDim.x + threadIdx.x;
  if (i >= 128 * 128) return;
  int j = i >> 7, k = i & 127;
  int ch = k >> 3, e = k & 7;
  int off = j * 256 + ((ch * 16) ^ ((j & 7) << 4)) + e * 2;
  *(unsigned short*)(img + off) = f2bf(lin_w[i]);
}

// ---------------- GEMM1: [P_f32 | Q_bf16] = X.h @ Wpq^T, K=128 single-stage ----------------
__global__ __launch_bounds__(512, 2) void k_gemm1(const unsigned short* __restrict__ X,
                                                   const unsigned char* __restrict__ img,
                                                   float* __restrict__ P,
                                                   unsigned short* __restrict__ Qb) {
  __shared__ __align__(16) unsigned char lds[98304];  // A 32KB @0, B 64KB @32768
  int tid = threadIdx.x;
  int w = tid >> 6, lane = tid & 63;
  int wr = w >> 2, wc = w & 3;
  int l16 = lane & 15, lhi = lane >> 4;
  int row0 = blockIdx.x * 128;
  const char* Xb = (const char*)X;
  // stage A: 4 issues/wave, per-lane inverse-swizzled source
#pragma unroll
  for (int j = 0; j < 4; j++) {
    int off = w * 4096 + j * 1024 + lane * 16;
    int r = off >> 8, pos = off & 255;
    int ch = (pos ^ ((r & 7) << 4)) >> 4;
    gload16(Xb + (size_t)(row0 + r) * 1280 + ch * 16, lds + w * 4096 + j * 1024);
  }
  // stage B: 8 issues/wave, linear (image pre-swizzled)
#pragma unroll
  for (int j = 0; j < 8; j++) {
    int off = w * 8192 + j * 1024;
    gload16(img + off + lane * 16, lds + 32768 + off);
  }
  __syncthreads();
  f32x4 acc[4][4];
#pragma unroll
  for (int m = 0; m < 4; m++)
#pragma unroll
    for (int nn = 0; nn < 4; nn++) acc[m][nn] = (f32x4){0.f, 0.f, 0.f, 0.f};
#pragma unroll
  for (int ks = 0; ks < 4; ks++) {
    int pb = ks * 64 + lhi * 16;
    bf16x8 af[4], bfr[4];
#pragma unroll
    for (int m = 0; m < 4; m++) af[m] = rf256(lds, wr * 64 + m * 16 + l16, pb);
#pragma unroll
    for (int nn = 0; nn < 4; nn++) {
      int brow = (nn >> 1) * 128 + wc * 32 + (nn & 1) * 16 + l16;
      bfr[nn] = rf256(lds + 32768, brow, pb);
    }
#pragma unroll
    for (int m = 0; m < 4; m++)
#pragma unroll
      for (int nn = 0; nn < 4; nn++)
        acc[m][nn] = __builtin_amdgcn_mfma_f32_16x16x32_bf16(af[m], bfr[nn], acc[m][nn], 0, 0, 0);
  }
#pragma unroll
  for (int m = 0; m < 4; m++)
#pragma unroll
    for (int j = 0; j < 2; j++)
#pragma unroll
      for (int i = 0; i < 4; i++) {
        int r = row0 + wr * 64 + m * 16 + lhi * 4 + i;
        int c = wc * 32 + j * 16 + l16;
        P[(size_t)r * 128 + c] = acc[m][j][i];
        Qb[(size_t)r * 128 + c] = f2bf(acc[m][2 + j][i]);
      }
}

// ---------------- aggregation ----------------
__global__ __launch_bounds__(256) void k_agg(const float* __restrict__ P,
                                              const unsigned short* __restrict__ Qb,
                                              const int* __restrict__ row_start,
                                              const int* __restrict__ edge_src,
                                              const float* __restrict__ pre_b,
                                              const float* __restrict__ adl,
                                              unsigned short* __restrict__ X,  // writes agg part
                                              float* __restrict__ scale,
                                              float* __restrict__ inv_scale, int n) {
  int gtid = blockIdx.x * blockDim.x + threadIdx.x;
  int v = gtid >> 6;
  int lane = threadIdx.x & 63;
  if (v >= n) return;
  int r0 = row_start[v], r1 = row_start[v + 1];
  int dg = r1 - r0;
  float s0 = 0.f, s1 = 0.f, q0 = 0.f, q1 = 0.f;
  float mn0 = INFINITY, mn1 = INFINITY, mx0 = -INFINITY, mx1 = -INFINITY;
  for (int e = r0; e < r1; e++) {
    int s = edge_src[e];
    unsigned u = *(const unsigned*)(Qb + (size_t)s * 128 + 2 * lane);
    float qx = __uint_as_float(u << 16);
    float qy = __uint_as_float(u & 0xffff0000u);
    s0 += qx; s1 += qy;
    q0 += qx * qx; q1 += qy * qy;
    mn0 = fminf(mn0, qx); mn1 = fminf(mn1, qy);
    mx0 = fmaxf(mx0, qx); mx1 = fmaxf(mx1, qy);
  }
  float degf = (float)dg;
  float invd = 1.0f / fmaxf(degf, 1.0f);
  float c0 = P[(size_t)v * 128 + 2 * lane] + pre_b[2 * lane];
  float c1 = P[(size_t)v * 128 + 2 * lane + 1] + pre_b[2 * lane + 1];
  float meanq0 = s0 * invd, meanq1 = s1 * invd;
  float var0 = fmaxf(q0 * invd - meanq0 * meanq0, 0.f);
  float var1 = fmaxf(q1 * invd - meanq1 * meanq1, 0.f);
  float std0 = sqrtf(var0 + 1e-5f), std1 = sqrtf(var1 + 1e-5f);
  float mean0, mean1, omn0, omn1, omx0, omx1;
  if (dg > 0) {
    mean0 = c0 + meanq0; mean1 = c1 + meanq1;
    omn0 = c0 + mn0; omn1 = c1 + mn1;
    omx0 = c0 + mx0; omx1 = c1 + mx1;
  } else {
    mean0 = mean1 = omn0 = omn1 = omx0 = omx1 = 0.f;
  }
  unsigned short* row = X + (size_t)v * 640 + 128;
  ushort2 w0; w0.x = f2bf(mean0); w0.y = f2bf(mean1);
  ushort2 w1; w1.x = f2bf(omn0);  w1.y = f2bf(omn1);
  ushort2 w2; w2.x = f2bf(omx0);  w2.y = f2bf(omx1);
  ushort2 w3; w3.x = f2bf(std0);  w3.y = f2bf(std1);
  *(ushort2*)(row + 2 * lane) = w0;
  *(ushort2*)(row + 128 + 2 * lane) = w1;
  *(ushort2*)(row + 256 + 2 * lane) = w2;
  *(ushort2*)(row + 384 + 2 * lane) = w3;
  if (lane == 0) {
    float sc = logf(fmaxf(degf, 1.0f) + 1.0f) / adl[0];
    scale[v] = sc;
    inv_scale[v] = 1.0f / sc;
  }
}

// ---------------- fused GEMM2 (K=640, 3-group combine) + lin GEMM + relu ----------------
__global__ __launch_bounds__(512, 2) void k_fused(const unsigned short* __restrict__ X,
                                                   const unsigned char* __restrict__ Bimg,
                                                   const unsigned char* __restrict__ Limg,
                                                   const float* __restrict__ scale,
                                                   const float* __restrict__ invs,
                                                   const float* __restrict__ post_b,
                                                   const float* __restrict__ lin_b,
                                                   unsigned short* __restrict__ Xh,
                                                   float* __restrict__ Fout,
                                                   int M, int write_f32) {
  // buf b: A[16KB] @ b*65536, B[48KB] @ b*65536+16384. Phase-B: lin @0 (32KB), y @32768 (32KB)
  __shared__ __align__(16) unsigned char lds[131072];
  int tid = threadIdx.x;
  int w = tid >> 6, lane = tid & 63;
  int wr = w >> 2, wc = w & 3;
  int l16 = lane & 15, lhi = lane >> 4;
  int row0 = blockIdx.x * 128;
  const char* Xb = (const char*)X;
  // precompute A-stage per-lane sources (inverse-swizzled)
  const char* srcA[2];
  unsigned dstA[2];
#pragma unroll
  for (int j = 0; j < 2; j++) {
    int off = (w * 2 + j) * 1024 + lane * 16;
    int r = off >> 7, pos = off & 127;
    int ch = (pos ^ ((r & 7) << 4)) >> 4;
    srcA[j] = Xb + (size_t)(row0 + r) * 1280 + ch * 16;
    dstA[j] = (w * 2 + j) * 1024;
  }
  const unsigned char* srcB = Bimg + w * 6144 + lane * 16;
  unsigned dstB = 16384 + w * 6144;

  f32x4 acc[4][6];
#pragma unroll
  for (int m = 0; m < 4; m++)
#pragma unroll
    for (int f = 0; f < 6; f++) acc[m][f] = (f32x4){0.f, 0.f, 0.f, 0.f};

#define STAGE_AB(buf, kt)                                                        \
  do {                                                                           \
    unsigned base = (buf) * 65536u;                                              \
    _Pragma("unroll") for (int j = 0; j < 2; j++)                                \
        gload16(srcA[j] + (kt) * 128, lds + base + dstA[j]);                     \
    _Pragma("unroll") for (int j = 0; j < 6; j++)                                \
        gload16(srcB + (size_t)(kt) * 49152 + j * 1024, lds + base + dstB + j * 1024); \
  } while (0)

#define COMPUTE_A(buf)                                                           \
  do {                                                                           \
    const unsigned char* LA = lds + (buf) * 65536u;                              \
    const unsigned char* LB = LA + 16384;                                        \
    _Pragma("unroll") for (int ks = 0; ks < 2; ks++) {                           \
      int pb = ks * 64 + lhi * 16;                                               \
      bf16x8 af[4], bfr[6];                                                      \
      _Pragma("unroll") for (int m = 0; m < 4; m++)                              \
          af[m] = rf128(LA, wr * 64 + m * 16 + l16, pb);                         \
      _Pragma("unroll") for (int f = 0; f < 6; f++)                              \
          bfr[f] = rf128(LB, (f >> 1) * 128 + wc * 32 + (f & 1) * 16 + l16, pb); \
      _Pragma("unroll") for (int m = 0; m < 4; m++)                              \
          _Pragma("unroll") for (int f = 0; f < 6; f++)                          \
              acc[m][f] =                                                        \
                  __builtin_amdgcn_mfma_f32_16x16x32_bf16(af[m], bfr[f], acc[m][f], 0, 0, 0); \
    }                                                                            \
  } while (0)

  STAGE_AB(0, 0);
  __syncthreads();
  for (int kt = 0; kt < 9; kt++) {
    STAGE_AB((kt + 1) & 1, kt + 1);
    COMPUTE_A(kt & 1);
    __syncthreads();
  }
  // prefetch lin image into buf0 region while computing final tile (buf1)
#pragma unroll
  for (int j = 0; j < 4; j++) {
    int off = w * 4096 + j * 1024;
    gload16(Limg + off + lane * 16, lds + off);
  }
  COMPUTE_A(1);

  // combine epilogue -> y into LDS @32768 (256B swizzled rows)
#pragma unroll
  for (int m = 0; m < 4; m++)
#pragma unroll
    for (int i = 0; i < 4; i++) {
      int rl = wr * 64 + m * 16 + lhi * 4 + i;
      int r = row0 + rl;
      float s = scale[r], iv = invs[r];
      int swz = (rl & 7) << 4;
#pragma unroll
      for (int j = 0; j < 2; j++) {
        int c = wc * 32 + j * 16 + l16;
        float v = acc[m][j][i] + s * acc[m][2 + j][i] + iv * acc[m][4 + j][i] + post_b[c];
        *(unsigned short*)(lds + 32768 + rl * 256 + ((2 * c) ^ swz)) = f2bf(v);
      }
    }
  __syncthreads();  // drains lin stage (vmcnt) + makes y visible

  // phase B: h = relu(y @ lin^T + lin_b)
  f32x4 acc2[4][2];
#pragma unroll
  for (int m = 0; m < 4; m++)
#pragma unroll
    for (int j = 0; j < 2; j++) acc2[m][j] = (f32x4){0.f, 0.f, 0.f, 0.f};
#pragma unroll
  for (int ks = 0; ks < 4; ks++) {
    int pb = ks * 64 + lhi * 16;
    bf16x8 af[4], bfr[2];
#pragma unroll
    for (int m = 0; m < 4; m++) af[m] = rf256(lds + 32768, wr * 64 + m * 16 + l16, pb);
#pragma unroll
    for (int j = 0; j < 2; j++) bfr[j] = rf256(lds, wc * 32 + j * 16 + l16, pb);
#pragma unroll
    for (int m = 0; m < 4; m++)
#pragma unroll
      for (int j = 0; j < 2; j++)
        acc2[m][j] = __builtin_amdgcn_mfma_f32_16x16x32_bf16(af[m], bfr[j], acc2[m][j], 0, 0, 0);
  }
#pragma unroll
  for (int m = 0; m < 4; m++)
#pragma unroll
    for (int j = 0; j < 2; j++)
#pragma unroll
      for (int i = 0; i < 4; i++) {
        int r = row0 + wr * 64 + m * 16 + lhi * 4 + i;
        int c = wc * 32 + j * 16 + l16;
        float v = fmaxf(acc2[m][j][i] + lin_b[c], 0.0f);
        Xh[(size_t)r * 640 + c] = f2bf(v);
        if (write_f32 && r < M) Fout[(size_t)r * 128 + c] = v;
      }
#undef STAGE_AB
#undef COMPUTE_A
}

// ---------------- host ----------------
extern "C" void kernel_launch(void* const* d_in, const int* in_sizes, int n_in,
                              void* d_out, int out_size, void* d_ws, size_t ws_size,
                              hipStream_t stream) {
  const float* x = (const float*)d_in[0];
  const int* eidx = (const int*)d_in[1];
  int n = in_sizes[0] / 128;
  int E = in_sizes[1] / 2;
  int n_pad = (n + 127) & ~127;
  const int* src = eidx;
  const int* dst = eidx + E;

  const float *pre_w[5], *pre_b[5], *adl[5], *post_w[5], *post_b[5], *lin_w[5], *lin_b[5];
  for (int i = 0; i < 5; i++) {
    pre_w[i] = (const float*)d_in[2 + i * 7 + 0];
    pre_b[i] = (const float*)d_in[2 + i * 7 + 1];
    adl[i] = (const float*)d_in[2 + i * 7 + 2];
    post_w[i] = (const float*)d_in[2 + i * 7 + 3];
    post_b[i] = (const float*)d_in[2 + i * 7 + 4];
    lin_w[i] = (const float*)d_in[2 + i * 7 + 5];
    lin_b[i] = (const float*)d_in[2 + i * 7 + 6];
  }

  char* ws = (char*)d_ws;
  size_t off = 0;
  auto alloc = [&](size_t bytes) {
    char* p = ws + off;
    off += (bytes + 255) & ~(size_t)255;
    return p;
  };
  unsigned short* X = (unsigned short*)alloc((size_t)n_pad * 640 * 2);  // [h | agg]
  float* P = (float*)alloc((size_t)n_pad * 128 * 4);
  unsigned short* Qb = (unsigned short*)alloc((size_t)n_pad * 128 * 2);
  float* scale = (float*)alloc((size_t)n_pad * 4);
  float* invs = (float*)alloc((size_t)n_pad * 4);
  int* deg = (int*)alloc((size_t)n * 4);
  int* row_start = (int*)alloc((size_t)(n + 1) * 4);
  int* cursor = (int*)alloc((size_t)n * 4);
  int* edge_src = (int*)alloc((size_t)E * 4);
  int nb = (n + 1023) / 1024;
  int* bsum = (int*)alloc((size_t)nb * 4);
  int* boff = (int*)alloc((size_t)nb * 4);
  unsigned char *Wpq[5], *Bpost[5], *Lin[5];
  for (int i = 0; i < 5; i++) {
    Wpq[i] = (unsigned char*)alloc(65536);
    Bpost[i] = (unsigned char*)alloc(491520);
    Lin[i] = (unsigned char*)alloc(32768);
  }

  hipMemsetAsync(deg, 0, (size_t)n * 4, stream);
  k_hist<<<(E + 255) / 256, 256, 0, stream>>>(dst, deg, E);
  k_scan_part<<<nb, 256, 0, stream>>>(deg, bsum, n);
  k_scan_bsum<<<1, 64, 0, stream>>>(bsum, boff, row_start, nb, n);
  k_scan_final<<<nb, 256, 0, stream>>>(deg, boff, row_start, cursor, n);
  k_scatter<<<(E + 255) / 256, 256, 0, stream>>>(src, dst, cursor, edge_src, E);
  k_cast<<<(n * 32 + 255) / 256, 256, 0, stream>>>(x, X, n);
  for (int i = 0; i < 5; i++) {
    k_repack_pq<<<(256 * 128 + 255) / 256, 256, 0, stream>>>(pre_w[i], Wpq[i]);
    k_repack_post<<<(384 * 640 + 255) / 256, 256, 0, stream>>>(post_w[i], Bpost[i]);
    k_repack_lin<<<(128 * 128 + 255) / 256, 256, 0, stream>>>(lin_w[i], Lin[i]);
  }

  int gblocks = n_pad / 128;
  for (int L = 0; L < 5; L++) {
    k_gemm1<<<gblocks, 512, 0, stream>>>(X, Wpq[L], P, Qb);
    k_agg<<<(n + 3) / 4, 256, 0, stream>>>(P, Qb, row_start, edge_src, pre_b[L], adl[L], X,
                                           scale, invs, n);
    k_fused<<<gblocks, 512, 0, stream>>>(X, Bpost[L], Lin[L], scale, invs, post_b[L], lin_b[L],
                                         X, (float*)d_out, n, (L == 4) ? 1 : 0);
  }
}

// Round 5
// 637.097 us; speedup vs baseline: 1.5502x; 1.0157x over previous
//
#include <hip/hip_runtime.h>

typedef short bf16x8 __attribute__((ext_vector_type(8)));
typedef float f32x4 __attribute__((ext_vector_type(4)));

__device__ __forceinline__ unsigned short f2bf(float f) {
  unsigned u = __float_as_uint(f);
  u += 0x7fffu + ((u >> 16) & 1u);
  return (unsigned short)(u >> 16);
}

__device__ __forceinline__ float bf2f(unsigned short h) {
  return __uint_as_float(((unsigned)h) << 16);
}

__device__ __forceinline__ void gload16(const void* g, void* l) {
  __builtin_amdgcn_global_load_lds((const __attribute__((address_space(1))) void*)g,
                                   (__attribute__((address_space(3))) void*)l, 16, 0, 0);
}

// 128B-row swizzled fragment read (64 bf16 per row)
__device__ __forceinline__ bf16x8 rf128(const unsigned char* lds, int row, int pb) {
  return *(const bf16x8*)(lds + row * 128 + (pb ^ ((row & 7) << 4)));
}
// 256B-row swizzled fragment read (128 bf16 per row)
__device__ __forceinline__ bf16x8 rf256(const unsigned char* lds, int row, int pb) {
  return *(const bf16x8*)(lds + row * 256 + (pb ^ ((row & 7) << 4)));
}

// ---------------- CSR build ----------------
__global__ void k_hist(const int* __restrict__ dst, int* __restrict__ deg, int E) {
  int e = blockIdx.x * blockDim.x + threadIdx.x;
  if (e < E) atomicAdd(&deg[dst[e]], 1);
}

__global__ __launch_bounds__(256) void k_scan_part(const int* __restrict__ deg,
                                                    int* __restrict__ bsum, int n) {
  int b = blockIdx.x, t = threadIdx.x;
  int base = b * 1024 + t * 4;
  int s = 0;
#pragma unroll
  for (int i = 0; i < 4; i++) {
    int idx = base + i;
    if (idx < n) s += deg[idx];
  }
  for (int off = 1; off < 64; off <<= 1) s += __shfl_xor(s, off);
  __shared__ int ws[4];
  if ((t & 63) == 0) ws[t >> 6] = s;
  __syncthreads();
  if (t == 0) bsum[b] = ws[0] + ws[1] + ws[2] + ws[3];
}

__global__ void k_scan_bsum(const int* __restrict__ bsum, int* __restrict__ boff,
                            int* __restrict__ row_start, int nb, int n) {
  int t = threadIdx.x;  // single wave, nb <= 64
  int orig = (t < nb) ? bsum[t] : 0;
  int v = orig;
  for (int off = 1; off < 64; off <<= 1) {
    int u = __shfl_up(v, off);
    if (t >= off) v += u;
  }
  if (t < nb) boff[t] = v - orig;
  if (t == nb - 1) row_start[n] = v;
}

__global__ __launch_bounds__(256) void k_scan_final(const int* __restrict__ deg,
                                                     const int* __restrict__ boff,
                                                     int* __restrict__ row_start,
                                                     int* __restrict__ cursor, int n) {
  int b = blockIdx.x, t = threadIdx.x;
  int lane = t & 63, wid = t >> 6;
  int base = b * 1024 + t * 4;
  int v[4];
  int s = 0;
#pragma unroll
  for (int i = 0; i < 4; i++) {
    int idx = base + i;
    v[i] = (idx < n) ? deg[idx] : 0;
    s += v[i];
  }
  int sc = s;
  for (int off = 1; off < 64; off <<= 1) {
    int u = __shfl_up(sc, off);
    if (lane >= off) sc += u;
  }
  __shared__ int ws[4];
  if (lane == 63) ws[wid] = sc;
  __syncthreads();
  int wbase = 0;
  for (int i = 0; i < wid; i++) wbase += ws[i];
  int run = boff[b] + wbase + sc - s;
#pragma unroll
  for (int i = 0; i < 4; i++) {
    int idx = base + i;
    if (idx < n) {
      row_start[idx] = run;
      cursor[idx] = run;
      run += v[i];
    }
  }
}

__global__ void k_scatter(const int* __restrict__ src, const int* __restrict__ dst,
                          int* __restrict__ cursor, int* __restrict__ edge_src, int E) {
  int e = blockIdx.x * blockDim.x + threadIdx.x;
  if (e < E) {
    int pos = atomicAdd(&cursor[dst[e]], 1);
    edge_src[pos] = src[e];
  }
}

// ---------------- cast x -> X.h (row stride 640) ----------------
__global__ void k_cast(const float* __restrict__ x, unsigned short* __restrict__ X, int n) {
  int i = blockIdx.x * blockDim.x + threadIdx.x;  // one per 4 floats
  if (i >= n * 32) return;
  int r = i >> 5, c = (i & 31) * 4;
  float4 v = *(const float4*)(x + (size_t)r * 128 + c);
  ushort4 o;
  o.x = f2bf(v.x); o.y = f2bf(v.y); o.z = f2bf(v.z); o.w = f2bf(v.w);
  *(ushort4*)(X + (size_t)r * 640 + c) = o;
}

// ---------------- fold: Whg[g][j][k] = sum_f Wc_g[j,f] * pre_w[f, k<128]; biasg ----------------
// Wc_g[j,f] = sum_{a=0..2} post_w[j*1664 + g*512 + 128 + a*128 + f]
// biasg[g*128+j] = Wc_g[j,:] @ pre_b  (+ post_b[j] for g==0)
__global__ __launch_bounds__(256) void k_fold(const float* __restrict__ post_w,
                                               const float* __restrict__ pre_w,
                                               const float* __restrict__ pre_b,
                                               const float* __restrict__ post_b,
                                               float* __restrict__ Whg,
                                               float* __restrict__ biasg) {
  int id = blockIdx.x * blockDim.x + threadIdx.x;
  if (id >= 3 * 128 * 128) return;
  int g = id >> 14;
  int rem = id & 16383;
  int j = rem >> 7, k = rem & 127;
  const float* pw = post_w + j * 1664 + g * 512 + 128;
  float acc = 0.f, bacc = 0.f;
  for (int f = 0; f < 128; f++) {
    float wc = pw[f] + pw[128 + f] + pw[256 + f];
    acc += wc * pre_w[f * 256 + k];
    if (k == 0) bacc += wc * pre_b[f];
  }
  Whg[id] = acc;
  if (k == 0) biasg[g * 128 + j] = bacc + ((g == 0) ? post_b[j] : 0.f);
}

// ---------------- weight repacks into pre-swizzled LDS images ----------------
// Bpost image: 10 K-tiles x (384 rows x 128B swizzled) = 480KB; h-part gets folded Whg
__global__ void k_repack_post(const float* __restrict__ post_w, const float* __restrict__ Whg,
                              unsigned char* __restrict__ img) {
  int i = blockIdx.x * blockDim.x + threadIdx.x;
  if (i >= 384 * 640) return;
  int r = i / 640, k = i - r * 640;
  int g = r >> 7, jj = r & 127;
  float v;
  if (k < 128) v = ((g == 0) ? post_w[jj * 1664 + k] : 0.0f) + Whg[(g * 128 + jj) * 128 + k];
  else v = post_w[jj * 1664 + g * 512 + 128 + (k - 128)];
  int kt = k >> 6, kl = k & 63;
  int ch = kl >> 3, e = kl & 7;
  int off = kt * 49152 + r * 128 + ((ch * 16) ^ ((r & 7) << 4)) + e * 2;
  *(unsigned short*)(img + off) = f2bf(v);
}

// Wq image: 128 rows x 256B (K=128 swizzled) from pre_w[:, 128:]
__global__ void k_repack_q(const float* __restrict__ pre_w, unsigned char* __restrict__ img) {
  int i = blockIdx.x * blockDim.x + threadIdx.x;
  if (i >= 128 * 128) return;
  int j = i >> 7, k = i & 127;
  int ch = k >> 3, e = k & 7;
  int off = j * 256 + ((ch * 16) ^ ((j & 7) << 4)) + e * 2;
  *(unsigned short*)(img + off) = f2bf(pre_w[j * 256 + 128 + k]);
}

// lin image: 128 rows x 256B (K=128, swizzled) = 32KB
__global__ void k_repack_lin(const float* __restrict__ lin_w, unsigned char* __restrict__ img) {
  int i = blockIdx.x * blockDim.x + threadIdx.x;
  if (i >= 128 * 128) return;
  int j = i >> 7, k = i & 127;
  int ch = k >> 3, e = k & 7;
  int off = j * 256 + ((ch * 16) ^ ((j & 7) << 4)) + e * 2;
  *(unsigned short*)(img + off) = f2bf(lin_w[i]);
}

// ---------------- GEMM1 (layer 0 only): Qb = X.h @ Wq^T, K=128, N=128 ----------------
__global__ __launch_bounds__(512, 2) void k_gemm1(const unsigned short* __restrict__ X,
                                                   const unsigned char* __restrict__ Qimg,
                                                   unsigned short* __restrict__ Qb) {
  __shared__ __align__(16) unsigned char lds[65536];  // A 32KB @0, B 32KB @32768
  int tid = threadIdx.x;
  int w = tid >> 6, lane = tid & 63;
  int wr = w >> 2, wc = w & 3;
  int l16 = lane & 15, lhi = lane >> 4;
  int row0 = blockIdx.x * 128;
  const char* Xb = (const char*)X;
#pragma unroll
  for (int j = 0; j < 4; j++) {
    int off = w * 4096 + j * 1024 + lane * 16;
    int r = off >> 8, pos = off & 255;
    int ch = (pos ^ ((r & 7) << 4)) >> 4;
    gload16(Xb + (size_t)(row0 + r) * 1280 + ch * 16, lds + w * 4096 + j * 1024);
  }
#pragma unroll
  for (int j = 0; j < 4; j++) {
    int off = w * 4096 + j * 1024;
    gload16(Qimg + off + lane * 16, lds + 32768 + off);
  }
  __syncthreads();
  f32x4 acc[4][2];
#pragma unroll
  for (int m = 0; m < 4; m++)
#pragma unroll
    for (int j = 0; j < 2; j++) acc[m][j] = (f32x4){0.f, 0.f, 0.f, 0.f};
#pragma unroll
  for (int ks = 0; ks < 4; ks++) {
    int pb = ks * 64 + lhi * 16;
    bf16x8 af[4], bfr[2];
#pragma unroll
    for (int m = 0; m < 4; m++) af[m] = rf256(lds, wr * 64 + m * 16 + l16, pb);
#pragma unroll
    for (int j = 0; j < 2; j++) bfr[j] = rf256(lds + 32768, wc * 32 + j * 16 + l16, pb);
#pragma unroll
    for (int m = 0; m < 4; m++)
#pragma unroll
      for (int j = 0; j < 2; j++)
        acc[m][j] = __builtin_amdgcn_mfma_f32_16x16x32_bf16(af[m], bfr[j], acc[m][j], 0, 0, 0);
  }
#pragma unroll
  for (int m = 0; m < 4; m++)
#pragma unroll
    for (int j = 0; j < 2; j++)
#pragma unroll
      for (int i = 0; i < 4; i++) {
        int r = row0 + wr * 64 + m * 16 + lhi * 4 + i;
        int c = wc * 32 + j * 16 + l16;
        Qb[(size_t)r * 128 + c] = f2bf(acc[m][j][i]);
      }
}

// ---------------- aggregation (raw Q stats; deg==0 stores -c in mean/min/max) ----------------
__global__ __launch_bounds__(256) void k_agg(const unsigned short* __restrict__ Qb,
                                              const int* __restrict__ row_start,
                                              const int* __restrict__ edge_src,
                                              const unsigned short* __restrict__ X_h,
                                              const float* __restrict__ pre_w,
                                              const float* __restrict__ pre_b,
                                              const float* __restrict__ adl,
                                              unsigned short* __restrict__ X,
                                              float* __restrict__ scale,
                                              float* __restrict__ inv_scale, int n) {
  int gtid = blockIdx.x * blockDim.x + threadIdx.x;
  int v = gtid >> 6;
  int lane = threadIdx.x & 63;
  if (v >= n) return;
  int r0 = row_start[v], r1 = row_start[v + 1];
  int dg = r1 - r0;
  float m0, m1, n0, n1, x0, x1, sd0, sd1;
  if (dg > 0) {
    float s0 = 0.f, s1 = 0.f, q0 = 0.f, q1 = 0.f;
    float mn0 = INFINITY, mn1 = INFINITY, mx0 = -INFINITY, mx1 = -INFINITY;
    int e = r0;
    for (; e + 1 < r1; e += 2) {
      int sa = edge_src[e], sb = edge_src[e + 1];
      unsigned ua = *(const unsigned*)(Qb + (size_t)sa * 128 + 2 * lane);
      unsigned ub = *(const unsigned*)(Qb + (size_t)sb * 128 + 2 * lane);
      float ax = __uint_as_float(ua << 16), ay = __uint_as_float(ua & 0xffff0000u);
      float bx = __uint_as_float(ub << 16), by = __uint_as_float(ub & 0xffff0000u);
      s0 += ax + bx; s1 += ay + by;
      q0 += ax * ax + bx * bx; q1 += ay * ay + by * by;
      mn0 = fminf(mn0, fminf(ax, bx)); mn1 = fminf(mn1, fminf(ay, by));
      mx0 = fmaxf(mx0, fmaxf(ax, bx)); mx1 = fmaxf(mx1, fmaxf(ay, by));
    }
    if (e < r1) {
      int sa = edge_src[e];
      unsigned ua = *(const unsigned*)(Qb + (size_t)sa * 128 + 2 * lane);
      float ax = __uint_as_float(ua << 16), ay = __uint_as_float(ua & 0xffff0000u);
      s0 += ax; s1 += ay;
      q0 += ax * ax; q1 += ay * ay;
      mn0 = fminf(mn0, ax); mn1 = fminf(mn1, ay);
      mx0 = fmaxf(mx0, ax); mx1 = fmaxf(mx1, ay);
    }
    float invd = 1.0f / (float)dg;
    m0 = s0 * invd; m1 = s1 * invd;
    float var0 = fmaxf(q0 * invd - m0 * m0, 0.f);
    float var1 = fmaxf(q1 * invd - m1 * m1, 0.f);
    sd0 = sqrtf(var0 + 1e-5f); sd1 = sqrtf(var1 + 1e-5f);
    n0 = mn0; n1 = mn1; x0 = mx0; x1 = mx1;
  } else {
    // rare: cancel folded c-term by storing -c; std = sqrt(1e-5)
    int j0 = 2 * lane, j1 = 2 * lane + 1;
    float c0 = pre_b[j0], c1 = pre_b[j1];
    const unsigned short* hv = X_h + (size_t)v * 640;
    for (int k = 0; k < 128; k++) {
      float hk = bf2f(hv[k]);
      c0 += hk * pre_w[j0 * 256 + k];
      c1 += hk * pre_w[j1 * 256 + k];
    }
    m0 = n0 = x0 = -c0;
    m1 = n1 = x1 = -c1;
    sd0 = sd1 = sqrtf(1e-5f);
  }
  unsigned short* row = X + (size_t)v * 640 + 128;
  ushort2 w0; w0.x = f2bf(m0);  w0.y = f2bf(m1);
  ushort2 w1; w1.x = f2bf(n0);  w1.y = f2bf(n1);
  ushort2 w2; w2.x = f2bf(x0);  w2.y = f2bf(x1);
  ushort2 w3; w3.x = f2bf(sd0); w3.y = f2bf(sd1);
  *(ushort2*)(row + 2 * lane) = w0;
  *(ushort2*)(row + 128 + 2 * lane) = w1;
  *(ushort2*)(row + 256 + 2 * lane) = w2;
  *(ushort2*)(row + 384 + 2 * lane) = w3;
  if (lane == 0) {
    float degf = (float)dg;
    float sc = logf(fmaxf(degf, 1.0f) + 1.0f) / adl[0];
    scale[v] = sc;
    inv_scale[v] = 1.0f / sc;
  }
}

// ------- fused: post GEMM (K=640) + combine + lin GEMM + relu + next-layer Q GEMM -------
__global__ __launch_bounds__(512, 2) void k_fused(const unsigned short* __restrict__ X,
                                                   const unsigned char* __restrict__ Bimg,
                                                   const unsigned char* __restrict__ Limg,
                                                   const unsigned char* __restrict__ Qimg,
                                                   const float* __restrict__ scale,
                                                   const float* __restrict__ invs,
                                                   const float* __restrict__ biasg,
                                                   const float* __restrict__ lin_b,
                                                   unsigned short* __restrict__ Xh,
                                                   unsigned short* __restrict__ Qb,
                                                   float* __restrict__ Fout,
                                                   int M, int write_f32, int doC) {
  // phase A: buf b: A[16KB] @ b*65536, B[48KB] @ b*65536+16384
  // phase B: lin @0 (32KB), y @32768 (32KB)
  // phase C: h @65536 (32KB), Wq @98304 (32KB)
  __shared__ __align__(16) unsigned char lds[131072];
  int tid = threadIdx.x;
  int w = tid >> 6, lane = tid & 63;
  int wr = w >> 2, wc = w & 3;
  int l16 = lane & 15, lhi = lane >> 4;
  int row0 = blockIdx.x * 128;
  const char* Xb = (const char*)X;
  const char* srcA[2];
  unsigned dstA[2];
#pragma unroll
  for (int j = 0; j < 2; j++) {
    int off = (w * 2 + j) * 1024 + lane * 16;
    int r = off >> 7, pos = off & 127;
    int ch = (pos ^ ((r & 7) << 4)) >> 4;
    srcA[j] = Xb + (size_t)(row0 + r) * 1280 + ch * 16;
    dstA[j] = (w * 2 + j) * 1024;
  }
  const unsigned char* srcB = Bimg + w * 6144 + lane * 16;
  unsigned dstB = 16384 + w * 6144;

  f32x4 acc[4][6];
#pragma unroll
  for (int m = 0; m < 4; m++)
#pragma unroll
    for (int f = 0; f < 6; f++) acc[m][f] = (f32x4){0.f, 0.f, 0.f, 0.f};

#define STAGE_AB(buf, kt)                                                        \
  do {                                                                           \
    unsigned base = (buf) * 65536u;                                              \
    _Pragma("unroll") for (int j = 0; j < 2; j++)                                \
        gload16(srcA[j] + (kt) * 128, lds + base + dstA[j]);                     \
    _Pragma("unroll") for (int j = 0; j < 6; j++)                                \
        gload16(srcB + (size_t)(kt) * 49152 + j * 1024, lds + base + dstB + j * 1024); \
  } while (0)

#define COMPUTE_A(buf)                                                           \
  do {                                                                           \
    const unsigned char* LA = lds + (buf) * 65536u;                              \
    const unsigned char* LB = LA + 16384;                                        \
    _Pragma("unroll") for (int ks = 0; ks < 2; ks++) {                           \
      int pb = ks * 64 + lhi * 16;                                               \
      bf16x8 af[4], bfr[6];                                                      \
      _Pragma("unroll") for (int m = 0; m < 4; m++)                              \
          af[m] = rf128(LA, wr * 64 + m * 16 + l16, pb);                         \
      _Pragma("unroll") for (int f = 0; f < 6; f++)                              \
          bfr[f] = rf128(LB, (f >> 1) * 128 + wc * 32 + (f & 1) * 16 + l16, pb); \
      _Pragma("unroll") for (int m = 0; m < 4; m++)                              \
          _Pragma("unroll") for (int f = 0; f < 6; f++)                          \
              acc[m][f] =                                                        \
                  __builtin_amdgcn_mfma_f32_16x16x32_bf16(af[m], bfr[f], acc[m][f], 0, 0, 0); \
    }                                                                            \
  } while (0)

  STAGE_AB(0, 0);
  __syncthreads();
  for (int kt = 0; kt < 9; kt++) {
    STAGE_AB((kt + 1) & 1, kt + 1);
    COMPUTE_A(kt & 1);
    __syncthreads();
  }
  // prefetch lin image into @0 while computing final tile (buf1)
#pragma unroll
  for (int j = 0; j < 4; j++) {
    int off = w * 4096 + j * 1024;
    gload16(Limg + off + lane * 16, lds + off);
  }
  COMPUTE_A(1);

  // combine epilogue -> y into LDS @32768 (256B swizzled rows)
#pragma unroll
  for (int m = 0; m < 4; m++)
#pragma unroll
    for (int i = 0; i < 4; i++) {
      int rl = wr * 64 + m * 16 + lhi * 4 + i;
      int r = row0 + rl;
      float s = scale[r], iv = invs[r];
      int swz = (rl & 7) << 4;
#pragma unroll
      for (int j = 0; j < 2; j++) {
        int c = wc * 32 + j * 16 + l16;
        float v = acc[m][j][i] + s * acc[m][2 + j][i] + iv * acc[m][4 + j][i] + biasg[c] +
                  s * biasg[128 + c] + iv * biasg[256 + c];
        *(unsigned short*)(lds + 32768 + rl * 256 + ((2 * c) ^ swz)) = f2bf(v);
      }
    }
  __syncthreads();  // drains lin stage + makes y visible

  // issue next-layer Wq prefetch into @98304 (hides under phase B)
  if (doC) {
#pragma unroll
    for (int j = 0; j < 4; j++) {
      int off = w * 4096 + j * 1024;
      gload16(Qimg + off + lane * 16, lds + 98304 + off);
    }
  }

  // phase B: h = relu(y @ lin^T + lin_b)
  f32x4 acc2[4][2];
#pragma unroll
  for (int m = 0; m < 4; m++)
#pragma unroll
    for (int j = 0; j < 2; j++) acc2[m][j] = (f32x4){0.f, 0.f, 0.f, 0.f};
#pragma unroll
  for (int ks = 0; ks < 4; ks++) {
    int pb = ks * 64 + lhi * 16;
    bf16x8 af[4], bfr[2];
#pragma unroll
    for (int m = 0; m < 4; m++) af[m] = rf256(lds + 32768, wr * 64 + m * 16 + l16, pb);
#pragma unroll
    for (int j = 0; j < 2; j++) bfr[j] = rf256(lds, wc * 32 + j * 16 + l16, pb);
#pragma unroll
    for (int m = 0; m < 4; m++)
#pragma unroll
      for (int j = 0; j < 2; j++)
        acc2[m][j] = __builtin_amdgcn_mfma_f32_16x16x32_bf16(af[m], bfr[j], acc2[m][j], 0, 0, 0);
  }
  // h epilogue: write Xh global (+Fout), and h into LDS @65536 for phase C
#pragma unroll
  for (int m = 0; m < 4; m++)
#pragma unroll
    for (int j = 0; j < 2; j++)
#pragma unroll
      for (int i = 0; i < 4; i++) {
        int rl = wr * 64 + m * 16 + lhi * 4 + i;
        int r = row0 + rl;
        int c = wc * 32 + j * 16 + l16;
        float v = fmaxf(acc2[m][j][i] + lin_b[c], 0.0f);
        unsigned short hb = f2bf(v);
        Xh[(size_t)r * 640 + c] = hb;
        if (doC) *(unsigned short*)(lds + 65536 + rl * 256 + ((2 * c) ^ ((rl & 7) << 4))) = hb;
        if (write_f32 && r < M) Fout[(size_t)r * 128 + c] = v;
      }
  if (!doC) return;
  __syncthreads();  // h visible + Wq staged (vmcnt drained)

  // phase C: Qb_next = h @ Wq^T
  f32x4 acc3[4][2];
#pragma unroll
  for (int m = 0; m < 4; m++)
#pragma unroll
    for (int j = 0; j < 2; j++) acc3[m][j] = (f32x4){0.f, 0.f, 0.f, 0.f};
#pragma unroll
  for (int ks = 0; ks < 4; ks++) {
    int pb = ks * 64 + lhi * 16;
    bf16x8 af[4], bfr[2];
#pragma unroll
    for (int m = 0; m < 4; m++) af[m] = rf256(lds + 65536, wr * 64 + m * 16 + l16, pb);
#pragma unroll
    for (int j = 0; j < 2; j++) bfr[j] = rf256(lds + 98304, wc * 32 + j * 16 + l16, pb);
#pragma unroll
    for (int m = 0; m < 4; m++)
#pragma unroll
      for (int j = 0; j < 2; j++)
        acc3[m][j] = __builtin_amdgcn_mfma_f32_16x16x32_bf16(af[m], bfr[j], acc3[m][j], 0, 0, 0);
  }
#pragma unroll
  for (int m = 0; m < 4; m++)
#pragma unroll
    for (int j = 0; j < 2; j++)
#pragma unroll
      for (int i = 0; i < 4; i++) {
        int r = row0 + wr * 64 + m * 16 + lhi * 4 + i;
        int c = wc * 32 + j * 16 + l16;
        Qb[(size_t)r * 128 + c] = f2bf(acc3[m][j][i]);
      }
#undef STAGE_AB
#undef COMPUTE_A
}

// ---------------- host ----------------
extern "C" void kernel_launch(void* const* d_in, const int* in_sizes, int n_in,
                              void* d_out, int out_size, void* d_ws, size_t ws_size,
                              hipStream_t stream) {
  const float* x = (const float*)d_in[0];
  const int* eidx = (const int*)d_in[1];
  int n = in_sizes[0] / 128;
  int E = in_sizes[1] / 2;
  int n_pad = (n + 127) & ~127;
  const int* src = eidx;
  const int* dst = eidx + E;

  const float *pre_w[5], *pre_b[5], *adl[5], *post_w[5], *post_b[5], *lin_w[5], *lin_b[5];
  for (int i = 0; i < 5; i++) {
    pre_w[i] = (const float*)d_in[2 + i * 7 + 0];
    pre_b[i] = (const float*)d_in[2 + i * 7 + 1];
    adl[i] = (const float*)d_in[2 + i * 7 + 2];
    post_w[i] = (const float*)d_in[2 + i * 7 + 3];
    post_b[i] = (const float*)d_in[2 + i * 7 + 4];
    lin_w[i] = (const float*)d_in[2 + i * 7 + 5];
    lin_b[i] = (const float*)d_in[2 + i * 7 + 6];
  }

  char* ws = (char*)d_ws;
  size_t off = 0;
  auto alloc = [&](size_t bytes) {
    char* p = ws + off;
    off += (bytes + 255) & ~(size_t)255;
    return p;
  };
  unsigned short* X = (unsigned short*)alloc((size_t)n_pad * 640 * 2);  // [h | agg]
  unsigned short* Qb = (unsigned short*)alloc((size_t)n_pad * 128 * 2);
  float* scale = (float*)alloc((size_t)n_pad * 4);
  float* invs = (float*)alloc((size_t)n_pad * 4);
  int* deg = (int*)alloc((size_t)n * 4);
  int* row_start = (int*)alloc((size_t)(n + 1) * 4);
  int* cursor = (int*)alloc((size_t)n * 4);
  int* edge_src = (int*)alloc((size_t)E * 4);
  int nb = (n + 1023) / 1024;
  int* bsum = (int*)alloc((size_t)nb * 4);
  int* boff = (int*)alloc((size_t)nb * 4);
  float* Whg = (float*)alloc(3 * 128 * 128 * 4);  // reused per layer
  unsigned char *Bpost[5], *Lin[5], *Qimg[5];
  float* biasg[5];
  for (int i = 0; i < 5; i++) {
    Bpost[i] = (unsigned char*)alloc(491520);
    Lin[i] = (unsigned char*)alloc(32768);
    Qimg[i] = (unsigned char*)alloc(32768);
    biasg[i] = (float*)alloc(384 * 4);
  }

  hipMemsetAsync(deg, 0, (size_t)n * 4, stream);
  k_hist<<<(E + 255) / 256, 256, 0, stream>>>(dst, deg, E);
  k_scan_part<<<nb, 256, 0, stream>>>(deg, bsum, n);
  k_scan_bsum<<<1, 64, 0, stream>>>(bsum, boff, row_start, nb, n);
  k_scan_final<<<nb, 256, 0, stream>>>(deg, boff, row_start, cursor, n);
  k_scatter<<<(E + 255) / 256, 256, 0, stream>>>(src, dst, cursor, edge_src, E);
  k_cast<<<(n * 32 + 255) / 256, 256, 0, stream>>>(x, X, n);
  for (int i = 0; i < 5; i++) {
    k_fold<<<192, 256, 0, stream>>>(post_w[i], pre_w[i], pre_b[i], post_b[i], Whg, biasg[i]);
    k_repack_post<<<(384 * 640 + 255) / 256, 256, 0, stream>>>(post_w[i], Whg, Bpost[i]);
    k_repack_lin<<<(128 * 128 + 255) / 256, 256, 0, stream>>>(lin_w[i], Lin[i]);
    k_repack_q<<<(128 * 128 + 255) / 256, 256, 0, stream>>>(pre_w[i], Qimg[i]);
  }

  int gblocks = n_pad / 128;
  k_gemm1<<<gblocks, 512, 0, stream>>>(X, Qimg[0], Qb);
  for (int L = 0; L < 5; L++) {
    k_agg<<<(n + 3) / 4, 256, 0, stream>>>(Qb, row_start, edge_src, X, pre_w[L], pre_b[L],
                                           adl[L], X, scale, invs, n);
    k_fused<<<gblocks, 512, 0, stream>>>(X, Bpost[L], Lin[L], (L < 4) ? Qimg[L + 1] : Qimg[0],
                                         scale, invs, biasg[L], lin_b[L], X, Qb, (float*)d_out,
                                         n, (L == 4) ? 1 : 0, (L < 4) ? 1 : 0);
  }
}